// Round 7
// baseline (316.621 us; speedup 1.0000x reference)
//
#include <hip/hip_runtime.h>
#include <hip/hip_bf16.h>
#include <cstddef>

#define B_    128
#define D_    2048
#define C_    16522
#define BETA_INV 20.0f      // 1/0.05
#define LSTRIDE 16528       // padded logits row stride (floats)

#define NTILES 1033         // ceil(C/16)

typedef __bf16 bf16;
typedef bf16  bf16x8 __attribute__((ext_vector_type(8)));
typedef bf16  bf16x4 __attribute__((ext_vector_type(4)));
typedef float f32x4  __attribute__((ext_vector_type(4)));

// ws layout (bytes):
//   logits : [0, 8462336)                128*16528*4
//   A_pack : [8462336, 8986624)          128*2048*2  bf16 fragment-ordered
#define WS_APACK_OFF 8462336

// ---------------------------------------------------------------------------
// pack_a: inputs [128,2048] fp32 -> bf16 in MFMA A-fragment order.
// frag f = mtile*64 + kstep; element tid = f*64 + lane (bf16x8 each).
// A[m = mtile*16 + (lane&15)][k = kstep*32 + (lane>>4)*8 + j]
// Also zeroes the loss accumulator (stream-ordered before tail's atomics).
// ---------------------------------------------------------------------------
__global__ __launch_bounds__(256) void pack_a(const float* __restrict__ inp,
                                              bf16* __restrict__ ap,
                                              float* __restrict__ out) {
  const int tid  = blockIdx.x * 256 + threadIdx.x;   // 0..32767
  if (tid == 0) out[0] = 0.f;
  const int lane = tid & 63;
  const int ks   = (tid >> 6) & 63;
  const int mt   = tid >> 12;
  const int row  = mt * 16 + (lane & 15);
  const int col  = ks * 32 + (lane >> 4) * 8;
  const f32x4 v0 = *(const f32x4*)(inp + row * D_ + col);
  const f32x4 v1 = *(const f32x4*)(inp + row * D_ + col + 4);
  bf16x8 b;
  b[0] = (bf16)v0[0]; b[1] = (bf16)v0[1]; b[2] = (bf16)v0[2]; b[3] = (bf16)v0[3];
  b[4] = (bf16)v1[0]; b[5] = (bf16)v1[1]; b[6] = (bf16)v1[2]; b[7] = (bf16)v1[3];
  ((bf16x8*)ap)[tid] = b;
}

static __device__ __forceinline__ bf16x4 cvt4(const f32x4 v) {
  bf16x4 h;
  h[0] = (bf16)v[0]; h[1] = (bf16)v[1]; h[2] = (bf16)v[2]; h[3] = (bf16)v[3];
  return h;
}

// ---------------------------------------------------------------------------
// gemm, round 7: 2-deep chunk pipeline, 3 blocks/CU.
// Round-6 post-mortem: single-barrier full-tile staging gave only 2
// lockstep blocks/CU -> CU alternates pure-memory / pure-compute phases,
// memory idle during the whole 64-step k-loop (BW 2.3 TB/s). Now:
//   - BK=512 chunks, double-buffered 16KB LDS each (32 KB total ->
//     3 blocks/CU at __launch_bounds__(512,6), 24 waves/CU).
//   - 2-deep pipeline: during compute of chunk c, loads for c+1 AND c+2
//     are in flight (~2 compute phases > 900cyc HBM latency of slack).
//   - issue order per iter: load(c+2) -> compute(c) -> ds_write(c+1) ->
//     out_em store(c+1) -> barrier. Every vmcnt wait targets loads issued
//     BEFORE any pending stores, so no transitive store stall (round-2
//     lesson, verified per-wait).
//   - XOR swizzle byte^=(row&7)<<4 on ds_write and ds_read (round-6
//     scheme, measured-cheap conflicts).
// Copy-through em->out_em stays fused (same registers as staging).
// ---------------------------------------------------------------------------
__global__ __launch_bounds__(512, 6) void gemm_logits(
    const bf16*  __restrict__ ap,
    const float* __restrict__ em,
    float*       __restrict__ logits,
    float*       __restrict__ out_em)
{
  __shared__ bf16 sB[2][16 * 512];     // 2 x 16 KB, swizzled

  const int t    = threadIdx.x;
  const int lane = t & 63;
  const int w    = t >> 6;             // wave id 0..7 == m-tile index
  const int ml   = lane & 15;
  const int quad = lane >> 4;
  const int n0   = blockIdx.x * 16;
  const int r    = n0 + ml;
  const bool valid = r < C_;

  // staging rows for this wave: w and w+8 (same swizzle key: (w+8)&7 == w&7)
  const int row0 = w, row1 = w + 8;
  const int gr0 = (n0 + row0 < C_) ? (n0 + row0) : (C_ - 1);
  const int gr1 = (n0 + row1 < C_) ? (n0 + row1) : (C_ - 1);
  const f32x4* s0 = (const f32x4*)(em + (size_t)gr0 * D_);
  const f32x4* s1 = (const f32x4*)(em + (size_t)gr1 * D_);
  const int swz = (w & 7) << 4;

  f32x4 pre[2][4];   // pre[c&1] = chunk c's 4 f32x4 (2 per row)

#define LOADC(buf, c)                                        \
  do {                                                       \
    (buf)[0] = s0[(c) * 128 + lane];                         \
    (buf)[1] = s0[(c) * 128 + lane + 64];                    \
    (buf)[2] = s1[(c) * 128 + lane];                         \
    (buf)[3] = s1[(c) * 128 + lane + 64];                    \
  } while (0)

#define WRITEC(buf, c)                                                        \
  do {                                                                        \
    char* base = (char*)sB[(c) & 1];                                          \
    *(bf16x4*)(base + ((row0 * 1024 + lane * 8      ) ^ swz)) = cvt4((buf)[0]);\
    *(bf16x4*)(base + ((row0 * 1024 + lane * 8 + 512) ^ swz)) = cvt4((buf)[1]);\
    *(bf16x4*)(base + ((row1 * 1024 + lane * 8      ) ^ swz)) = cvt4((buf)[2]);\
    *(bf16x4*)(base + ((row1 * 1024 + lane * 8 + 512) ^ swz)) = cvt4((buf)[3]);\
  } while (0)

#define STOREC(buf, c)                                                  \
  do {                                                                  \
    if (n0 + row0 < C_) {                                               \
      f32x4* dd = (f32x4*)(out_em + (size_t)(n0 + row0) * D_);          \
      dd[(c) * 128 + lane]      = (buf)[0];                             \
      dd[(c) * 128 + lane + 64] = (buf)[1];                             \
    }                                                                   \
    if (n0 + row1 < C_) {                                               \
      f32x4* dd = (f32x4*)(out_em + (size_t)(n0 + row1) * D_);          \
      dd[(c) * 128 + lane]      = (buf)[2];                             \
      dd[(c) * 128 + lane + 64] = (buf)[3];                             \
    }                                                                   \
  } while (0)

  // prologue: chunk 0 staged, chunk 1 in flight
  LOADC(pre[0], 0);
  WRITEC(pre[0], 0);        // vmcnt waits pre[0] loads only (no stores yet)
  LOADC(pre[1], 1);         // issue c1 BEFORE c0's out_em stores
  STOREC(pre[0], 0);
  __syncthreads();

  f32x4 acc = {};
  const bf16x8* apc = (const bf16x8*)ap + (size_t)(w * 64) * 64 + lane;
  const int rswz  = (ml & 7) << 4;
  const int rbase = (ml << 10) + (quad << 4);

  #pragma unroll
  for (int c = 0; c < 4; ++c) {
    // issue loads for chunk c+2 (into the reg set freed by chunk c)
    if (c + 2 < 4) LOADC(pre[c & 1], c + 2);

    // compute chunk c from sB[c&1]
    const char* sb = (const char*)sB[c & 1];
    #pragma unroll
    for (int kk = 0; kk < 16; ++kk) {
      const bf16x8 bfrag =
          *(const bf16x8*)(sb + ((rbase + (kk << 6)) ^ rswz));
      acc = __builtin_amdgcn_mfma_f32_16x16x32_bf16(
          apc[(size_t)(c * 16 + kk) * 64], bfrag, acc, 0, 0, 0);
    }

    if (c + 1 < 4) {
      WRITEC(pre[(c + 1) & 1], c + 1);  // waits loads(c+1); pending stores ok
      STOREC(pre[(c + 1) & 1], c + 1);
      __syncthreads();
    }
  }

#undef LOADC
#undef WRITEC
#undef STOREC

  if (valid) {
    #pragma unroll
    for (int reg = 0; reg < 4; ++reg) {
      const int row = w * 16 + quad * 4 + reg;
      logits[row * LSTRIDE + r] = acc[reg] * BETA_INV;
    }
  }
}

// ---------------------------------------------------------------------------
// tail: fused row_loss (blocks 0..127, one block per sample row, full-row
// scan) and em_update (blocks 128..255). Branch is block-uniform.
// ---------------------------------------------------------------------------
__global__ __launch_bounds__(256) void tail(
    const float* __restrict__ logits,
    const int*   __restrict__ label,
    const float* __restrict__ inp,
    const float* __restrict__ em,
    const int*   __restrict__ epoch,
    float*       __restrict__ out,
    float*       __restrict__ out_em)
{
  __shared__ float rm[256], rs[256];
  __shared__ float cv[1536];
  __shared__ int   ci[1536];
  __shared__ float sly;
  __shared__ int   lbl[B_];
  __shared__ float red[4];

  const int t = threadIdx.x;

  if (blockIdx.x < B_) {
    // ---------------- row_loss: full row b, online lse + top-6 ----------
    const int b = blockIdx.x;
    const float* row = logits + b * LSTRIDE;
    const int y = label[b];

    float m = -INFINITY, s = 0.f, ly = -INFINITY;
    float tv[6]; int ti[6];
    #pragma unroll
    for (int q = 0; q < 6; ++q) { tv[q] = -INFINITY; ti[q] = -1; }

    for (int i = t; i < C_; i += 256) {
      const float v = row[i];
      if (v > m) { s = s * __expf(m - v) + 1.f; m = v; }
      else       { s += __expf(v - m); }
      if (i == y) ly = v;
      if (v > tv[5]) {
        tv[5] = v; ti[5] = i;
        #pragma unroll
        for (int q = 5; q > 0; --q)
          if (tv[q] > tv[q - 1]) {
            const float fv = tv[q]; tv[q] = tv[q - 1]; tv[q - 1] = fv;
            const int   fi = ti[q]; ti[q] = ti[q - 1]; ti[q - 1] = fi;
          }
      }
    }

    rm[t] = m; rs[t] = s;
    #pragma unroll
    for (int q = 0; q < 6; ++q) { cv[t * 6 + q] = tv[q]; ci[t * 6 + q] = ti[q]; }
    if (t == 0) sly = -INFINITY;
    __syncthreads();
    if (ly != -INFINITY) sly = ly;

    for (int off = 128; off >= 1; off >>= 1) {
      if (t < off) {
        const float m2 = rm[t + off], s2 = rs[t + off];
        const float M = fmaxf(rm[t], m2);
        rs[t] = rs[t] * __expf(rm[t] - M) + s2 * __expf(m2 - M);
        rm[t] = M;
      }
      __syncthreads();
    }

    if (t < 64) {   // wave 0: top-6 of 1536 candidates
      float otv[6]; int oti[6];
      for (int rr = 0; rr < 6; ++rr) {
        float bv = -INFINITY; int bi = -1, bs = -1;
        for (int u = 0; u < 24; ++u) {
          const int slot = t * 24 + u;
          const float v = cv[slot];
          if (v > bv) { bv = v; bi = ci[slot]; bs = slot; }
        }
        #pragma unroll
        for (int off = 32; off >= 1; off >>= 1) {
          const float ov = __shfl_down(bv, off);
          const int   oi = __shfl_down(bi, off);
          const int   os = __shfl_down(bs, off);
          if (ov > bv) { bv = ov; bi = oi; bs = os; }
        }
        bv = __shfl(bv, 0); bi = __shfl(bi, 0); bs = __shfl(bs, 0);
        if (bs >= t * 24 && bs < (t + 1) * 24) cv[bs] = -INFINITY;
        otv[rr] = bv; oti[rr] = bi;
      }
      if (t == 0) {
        const float lse = rm[0] + logf(rs[0]);
        float stop = 0.f; int intop = 0;
        #pragma unroll
        for (int q = 0; q < 6; ++q) {
          stop += otv[q];
          if (oti[q] == y) intop = 1;
        }
        const float lyv = sly;
        const float loss = intop ? (13.f * lse - lyv - 2.f * stop)
                                 : (15.f * lse - 3.f * lyv - 2.f * stop);
        atomicAdd(out, loss * (1.0f / 128.0f));
      }
    }
  } else {
    // ---------------- em_update: sample i = blockIdx.x - 128 ------------
    if (t < B_) lbl[t] = label[t];
    __syncthreads();

    const int i = blockIdx.x - B_;
    const int y = lbl[i];
    for (int j = 0; j < i; ++j)
      if (lbl[j] == y) return;          // uniform: all threads agree

    const float alpha = 0.01f * (float)epoch[0];
    const int lane = t & 63, wave = t >> 6;

    float rreg[8];
    #pragma unroll
    for (int u = 0; u < 8; ++u) rreg[u] = em[(size_t)y * D_ + t + u * 256];

    for (int j = i; j < B_; ++j) {
      if (lbl[j] != y) continue;        // uniform branch
      const float* x = inp + j * D_;
      float ss = 0.f;
      #pragma unroll
      for (int u = 0; u < 8; ++u) {
        rreg[u] = alpha * rreg[u] + (1.f - alpha) * x[t + u * 256];
        ss += rreg[u] * rreg[u];
      }
      #pragma unroll
      for (int off = 32; off >= 1; off >>= 1) ss += __shfl_down(ss, off);
      if (lane == 0) red[wave] = ss;
      __syncthreads();
      const float inv = 1.f / sqrtf(red[0] + red[1] + red[2] + red[3]);
      #pragma unroll
      for (int u = 0; u < 8; ++u) rreg[u] *= inv;
      __syncthreads();                  // red[] reused next chain step
    }

    #pragma unroll
    for (int u = 0; u < 8; ++u) out_em[(size_t)y * D_ + t + u * 256] = rreg[u];
  }
}

// ---------------------------------------------------------------------------
extern "C" void kernel_launch(void* const* d_in, const int* in_sizes, int n_in,
                              void* d_out, int out_size, void* d_ws, size_t ws_size,
                              hipStream_t stream) {
  const float* inp   = (const float*)d_in[0];
  const int*   label = (const int*)d_in[1];
  const float* em    = (const float*)d_in[2];
  const int*   epoch = (const int*)d_in[3];

  float* out    = (float*)d_out;
  float* out_em = out + 1;
  float* logits = (float*)d_ws;
  bf16*  apack  = (bf16*)((char*)d_ws + WS_APACK_OFF);

  pack_a      <<<dim3(128),    dim3(256), 0, stream>>>(inp, apack, out);
  gemm_logits <<<dim3(NTILES), dim3(512), 0, stream>>>(apack, em, logits, out_em);
  tail        <<<dim3(2 * B_), dim3(256), 0, stream>>>(logits, label, inp, em,
                                                       epoch, out, out_em);
}